// Round 8
// baseline (162.119 us; speedup 1.0000x reference)
//
#include <hip/hip_runtime.h>

typedef unsigned short u16;
typedef unsigned int u32;
typedef __attribute__((ext_vector_type(2))) unsigned int u32x2;
typedef __attribute__((ext_vector_type(4))) unsigned int u32x4;
typedef __attribute__((ext_vector_type(4))) unsigned short u16x4;
typedef __attribute__((ext_vector_type(8))) unsigned short u16x8;
typedef __attribute__((ext_vector_type(8))) short short8;
typedef __attribute__((ext_vector_type(4))) float f32x4;
typedef __attribute__((ext_vector_type(16))) float f32x16;

#define NHEAD 16
#define HDIM 64
#define SEQ 2048
#define MODELD 1024
#define MROWS 4096            // B*N
#define QKVCOLS 3072
// ATT_SCALE * log2(e), folded into q weights/bias so softmax uses exp2
#define QSCALE 0.18033688011112042f

#define WAITVM(N) asm volatile("s_waitcnt vmcnt(" #N ")" ::: "memory")

__device__ __forceinline__ u16 f2bf(float f) {
  union { float f; unsigned u; } v; v.f = f;
  unsigned r = v.u + 0x7FFFu + ((v.u >> 16) & 1u);
  return (u16)(r >> 16);
}

// packed f32x2 -> bf16x2 (RTNE), single instruction (T12)
__device__ __forceinline__ u32 cvtpk(float lo, float hi) {
  u32 r;
  asm("v_cvt_pk_bf16_f32 %0, %1, %2" : "=v"(r) : "v"(lo), "v"(hi));
  return r;
}

// v_permlane32_swap: a' = [a.lo32lanes | b.lo32lanes], b' = [a.hi | b.hi]
__device__ __forceinline__ void pl32(u32& a, u32& b) {
  asm("v_permlane32_swap_b32 %0, %1" : "+v"(a), "+v"(b));
}

__device__ __forceinline__ void gload_lds16(const void* g, void* l) {
  __builtin_amdgcn_global_load_lds((const __attribute__((address_space(1))) void*)g,
                                   (__attribute__((address_space(3))) void*)l, 16, 0, 0);
}

// ---------------- prep kernels ----------------

// f32 -> bf16, 4 elems/thread, exact grid
__global__ void prep_cast(const float* __restrict__ in, u16* __restrict__ outb) {
  int i = blockIdx.x * 256 + threadIdx.x;
  float4 v = *(const float4*)(in + (size_t)i * 4);
  u16x4 o = {f2bf(v.x), f2bf(v.y), f2bf(v.z), f2bf(v.w)};
  *(u16x4*)(outb + (size_t)i * 4) = o;
}

// mask -> additive f32 (0 / -1e30); parallel int32-vs-byte marshalling probe.
// 1 block x 1024 threads x 4 elems = 4096 (FIX: r7 wrote only 2048).
__global__ void prep_mask(const unsigned int* __restrict__ mraw, float* __restrict__ mf) {
  __shared__ int flag;
  const int tid = threadIdx.x;
  if (tid == 0) flag = 0;
  __syncthreads();
  if (mraw[tid] > 1u) flag = 1;   // race-benign
  __syncthreads();
  const int is_bytes = flag;
  const unsigned char* bp = (const unsigned char*)mraw;
#pragma unroll
  for (int j = 0; j < 4; ++j) {
    unsigned v = is_bytes ? (unsigned)bp[tid * 4 + j] : mraw[tid * 4 + j];
    mf[tid * 4 + j] = v ? 0.f : -1e30f;
  }
}

// combined qkv weight (bf16) with LoRA + base fold; q rows pre-scaled by ATT_SCALE*log2e
__global__ void prep_w(const float* __restrict__ wqkv,
                       const float* __restrict__ wqb, const float* __restrict__ bq,
                       const float* __restrict__ wqA, const float* __restrict__ wqB,
                       const float* __restrict__ wvb, const float* __restrict__ bv,
                       const float* __restrict__ wvA, const float* __restrict__ wvB,
                       u16* __restrict__ wcomb, float* __restrict__ biasc) {
  const int c = blockIdx.x;             // 0..3071
  const int t = c >> 10, hd = c & 1023;
  const int k0 = threadIdx.x * 4;
  float4 w = *(const float4*)(wqkv + (size_t)c * MODELD + k0);
  float a0 = w.x, a1 = w.y, a2 = w.z, a3 = w.w;
  if (t != 1) {
    const float* base = (t == 0 ? wqb : wvb) + (size_t)hd * MODELD + k0;
    const float* A = (t == 0 ? wqA : wvA);
    const float* Bm = (t == 0 ? wqB : wvB) + hd * 10;
    float4 bsv = *(const float4*)base;
    a0 += bsv.x; a1 += bsv.y; a2 += bsv.z; a3 += bsv.w;
#pragma unroll
    for (int j = 0; j < 10; ++j) {
      float bj = Bm[j] * 0.1f;               // LORA_SCALE = 1/R
      float4 av = *(const float4*)(A + (size_t)j * MODELD + k0);
      a0 += bj * av.x; a1 += bj * av.y; a2 += bj * av.z; a3 += bj * av.w;
    }
    if (t == 0) { a0 *= QSCALE; a1 *= QSCALE; a2 *= QSCALE; a3 *= QSCALE; }
  }
  u16x4 o = {f2bf(a0), f2bf(a1), f2bf(a2), f2bf(a3)};
  *(u16x4*)(wcomb + (size_t)c * MODELD + k0) = o;
  if (threadIdx.x == 0)
    biasc[c] = (t == 0) ? QSCALE * bq[hd] : ((t == 2) ? bv[hd] : 0.f);
}

// ---------------- 128x128 bf16 MFMA GEMM, BK=64, swizzled LDS ----------------
// MODE 0: scatter q row-major, k/v FRAGMENT-MAJOR (the flash kernel's LDS image);
// MODE 1: f32 + bias
template<int MODE>
__global__ __launch_bounds__(256) void gemm128(const u16* __restrict__ A, const u16* __restrict__ W,
                                               const float* __restrict__ bias,
                                               u16* __restrict__ oq, u16* __restrict__ ok, u16* __restrict__ ov,
                                               float* __restrict__ of) {
  __shared__ __align__(16) char lds[32768];
  const int tid = threadIdx.x;
  const int lane = tid & 63;
  const int wid = tid >> 6;
  const int wr = wid >> 1, wc = wid & 1;
  const int m0 = blockIdx.y << 7;
  const int n0 = blockIdx.x << 7;
  const int K = MODELD;

  f32x4 acc[4][4] = {};

  const int so = wid * 1024 + (lane << 4);
  for (int kt = 0; kt < K; kt += 64) {
#pragma unroll
    for (int c = 0; c < 4; ++c) {
      const int o = c * 4096 + so;
      const int row = o >> 7;
      const int colb = (o & 127) ^ ((row & 7) << 4);   // inverse-swizzled global source (m173)
      gload_lds16((const char*)(A + (size_t)(m0 + row) * K + kt) + colb, lds + (c * 4096 + wid * 1024));
      gload_lds16((const char*)(W + (size_t)(n0 + row) * K + kt) + colb, lds + (16384 + c * 4096 + wid * 1024));
    }
    __syncthreads();
#pragma unroll
    for (int ks = 0; ks < 2; ++ks) {
      short8 av[4], bv[4];
#pragma unroll
      for (int i = 0; i < 4; ++i) {
        const int arow = wr * 64 + i * 16 + (lane & 15);
        const int off = (ks * 64 + ((lane >> 4) << 4)) ^ ((lane & 7) << 4); // (row&7)==(lane&7)
        av[i] = *(const short8*)(lds + (arow << 7) + off);
        const int brow = wc * 64 + i * 16 + (lane & 15);
        bv[i] = *(const short8*)(lds + 16384 + (brow << 7) + off);
      }
#pragma unroll
      for (int i = 0; i < 4; ++i)
#pragma unroll
        for (int j = 0; j < 4; ++j)
          acc[i][j] = __builtin_amdgcn_mfma_f32_16x16x32_bf16(av[i], bv[j], acc[i][j], 0, 0, 0);
    }
    __syncthreads();
  }

  if (MODE == 0) {
#pragma unroll
    for (int j = 0; j < 4; ++j) {
      const int col = n0 + wc * 64 + j * 16 + (lane & 15);
      const int tsel = col >> 10;
      const int hd = col & 1023;
      const int hh = hd >> 6, d = hd & 63;
      const float bs = bias[col];
#pragma unroll
      for (int i = 0; i < 4; ++i) {
        const int rowb = m0 + wr * 64 + i * 16 + ((lane >> 4) << 2);
#pragma unroll
        for (int r = 0; r < 4; ++r) {
          const int row = rowb + r;
          const int b = row >> 11, kv = row & 2047;
          const int bh = b * NHEAD + hh;
          const u16 val = f2bf(acc[i][j][r] + bs);
          if (tsel == 0) {
            oq[((size_t)bh * SEQ + kv) * HDIM + d] = val;
          } else if (tsel == 1) {
            // K frag-major: tile=(kv>>6), sub=kvblk*4+ks, lane=(kv&31)+32*((d>>3)&1), j=d&7
            ok[((size_t)(bh * 32 + (kv >> 6))) * 4096 +
               (size_t)(((((kv >> 5) & 1) << 2) + (d >> 4)) * 512) +
               (size_t)((((kv & 31) + (((d >> 3) & 1) << 5)) << 3) + (d & 7))] = val;
          } else {
            // V frag-major: tile=(kv>>6), sub=dblk*4+s, lane=(d&31)+32*((kv>>3)&1), j=kv&7
            ov[((size_t)(bh * 32 + (kv >> 6))) * 4096 +
               (size_t)((((d >> 5) << 2) + ((kv >> 4) & 3)) * 512) +
               (size_t)((((d & 31) + (((kv >> 3) & 1) << 5)) << 3) + (kv & 7))] = val;
          }
        }
      }
    }
  } else {
#pragma unroll
    for (int j = 0; j < 4; ++j) {
      const int col = n0 + wc * 64 + j * 16 + (lane & 15);
      const float bs = bias[col];
#pragma unroll
      for (int i = 0; i < 4; ++i) {
        const int rowb = m0 + wr * 64 + i * 16 + ((lane >> 4) << 2);
#pragma unroll
        for (int r = 0; r < 4; ++r)
          of[(size_t)(rowb + r) * MODELD + col] = acc[i][j][r] + bs;
      }
    }
  }
}

// ---------------- flash attention ----------------
// 32x32x16 MFMA, swapped operands; P fully in-register via cvt_pk + permlane32_swap;
// frag-major K/V (linear lane*16 ds_reads, conflict-free); quad-buffered staging with
// raw s_barrier + counted vmcnt (never drained in-loop). 512 blocks XCD-pinned,
// 4 waves x 32 q-rows.
__global__ __launch_bounds__(256) void flash_attn(const u16* __restrict__ q, const u16* __restrict__ kfr,
                                                  const u16* __restrict__ vfr, const float* __restrict__ maskf,
                                                  u16* __restrict__ attnout) {
  // LDS: 4 x (K 8K | V 8K) bufs = 64K | mask f32 8K  = 72KB
  __shared__ __align__(16) char lds[73728];
  const int tid = threadIdx.x;
  const int lane = tid & 63, wid = tid >> 6;
  const int qi = lane & 31, h = lane >> 5;
  const int bid = blockIdx.x;
  const int bh = (bid & 7) * 4 + (bid >> 7);          // XCD-pinned: 4 heads per XCD
  const int q0 = ((bid >> 3) & 15) * 128;
  const int b = bh >> 4, hh = bh & 15;

  // Q B-frags: lane holds col=q=qi, k = 16ks + 8h + j
  const int token = q0 + wid * 32 + qi;
  short8 qf[4];
  {
    const u16* qp = q + ((size_t)bh * SEQ + token) * HDIM;
#pragma unroll
    for (int ks = 0; ks < 4; ++ks) qf[ks] = *(const short8*)(qp + ks * 16 + h * 8);
  }

  // stage mask (2048 f32 = 8KB) once
  {
    const char* ms = (const char*)(maskf + b * SEQ);
    gload_lds16(ms + tid * 16, lds + 65536 + tid * 16);
    gload_lds16(ms + 4096 + tid * 16, lds + 65536 + 4096 + tid * 16);
  }

  // frag-major staging: tile-contiguous 8KB blocks, pure linear copies
  const int so = tid << 4;
  const char* kg = (const char*)kfr + ((size_t)bh * 32) * 8192;
  const char* vg = (const char*)vfr + ((size_t)bh * 32) * 8192;
  auto stage = [&](int t) {
    char* kd = lds + ((t & 3) << 14);
    const char* ks = kg + (size_t)t * 8192;
    const char* vs = vg + (size_t)t * 8192;
    gload_lds16(ks + so, kd + so);
    gload_lds16(ks + 4096 + so, kd + 4096 + so);
    gload_lds16(vs + so, kd + 8192 + so);
    gload_lds16(vs + 4096 + so, kd + 12288 + so);
  };
  stage(0); stage(1); stage(2);     // + mask: 14 outstanding

  f32x16 o0 = {}, o1 = {};
  f32x4 ps = {0.f, 0.f, 0.f, 0.f};

  for (int t = 0; t < 32; ++t) {
    if (t < 30)      { WAITVM(8); }
    else if (t == 30){ WAITVM(4); }
    else             { WAITVM(0); }
    asm volatile("s_barrier" ::: "memory");
    if (t <= 28) stage(t + 3);

    char* kb = lds + ((t & 3) << 14);
    char* vb = kb + 8192;
    const char* mrow = lds + 65536 + (t << 8);

    // QK^T swapped: s_blk[reg] = S[kv=(reg&3)+8(reg>>2)+4h+32blk][q=qi]
    f32x16 s0 = {}, s1 = {};
    __builtin_amdgcn_s_setprio(1);
#pragma unroll
    for (int ks = 0; ks < 4; ++ks) {
      short8 ak0 = *(const short8*)(kb + (ks << 10) + (lane << 4));
      short8 ak1 = *(const short8*)(kb + 4096 + (ks << 10) + (lane << 4));
      s0 = __builtin_amdgcn_mfma_f32_32x32x16_bf16(ak0, qf[ks], s0, 0, 0, 0);
      s1 = __builtin_amdgcn_mfma_f32_32x32x16_bf16(ak1, qf[ks], s1, 0, 0, 0);
    }
    __builtin_amdgcn_s_setprio(0);

    // softmax: P = exp2(s + mask), psum in-register; pack to bf16x2
    u32 w[16];
#pragma unroll
    for (int blk = 0; blk < 2; ++blk) {
#pragma unroll
      for (int g = 0; g < 4; ++g) {
        f32x4 mk = *(const f32x4*)(mrow + blk * 128 + (g << 5) + (h << 4));
        float e0, e1, e2, e3;
        if (blk == 0) {
          e0 = exp2f(s0[4 * g + 0] + mk[0]); e1 = exp2f(s0[4 * g + 1] + mk[1]);
          e2 = exp2f(s0[4 * g + 2] + mk[2]); e3 = exp2f(s0[4 * g + 3] + mk[3]);
        } else {
          e0 = exp2f(s1[4 * g + 0] + mk[0]); e1 = exp2f(s1[4 * g + 1] + mk[1]);
          e2 = exp2f(s1[4 * g + 2] + mk[2]); e3 = exp2f(s1[4 * g + 3] + mk[3]);
        }
        ps[0] += e0; ps[1] += e1; ps[2] += e2; ps[3] += e3;
        w[blk * 8 + 2 * g] = cvtpk(e0, e1);
        w[blk * 8 + 2 * g + 1] = cvtpk(e2, e3);
      }
    }
    // redistribute to PV B-frags: in-place, frag s = (w[4s],w[4s+1],w[4s+2],w[4s+3])
    pl32(w[0], w[2]);  pl32(w[1], w[3]);
    pl32(w[4], w[6]);  pl32(w[5], w[7]);
    pl32(w[8], w[10]); pl32(w[9], w[11]);
    pl32(w[12], w[14]); pl32(w[13], w[15]);

    // PV swapped: O^T[d][q] += V . P
    __builtin_amdgcn_s_setprio(1);
#pragma unroll
    for (int s = 0; s < 4; ++s) {
      u32x4 pw = {w[4 * s], w[4 * s + 1], w[4 * s + 2], w[4 * s + 3]};
      short8 pf = __builtin_bit_cast(short8, pw);
      short8 av0 = *(const short8*)(vb + (s << 10) + (lane << 4));
      short8 av1 = *(const short8*)(vb + 4096 + (s << 10) + (lane << 4));
      o0 = __builtin_amdgcn_mfma_f32_32x32x16_bf16(av0, pf, o0, 0, 0, 0);
      o1 = __builtin_amdgcn_mfma_f32_32x32x16_bf16(av1, pf, o1, 0, 0, 0);
    }
    __builtin_amdgcn_s_setprio(0);
  }

  // lsum: own half (16 of 32 kv-rows per block, both blocks) + other h via one shuffle
  float l = (ps[0] + ps[1]) + (ps[2] + ps[3]);
  l += __shfl_xor(l, 32);
  const float inv = 1.0f / l;

  // O^T: lane owns column q=token; rows d = 32*dblk + 8g + 4h + {0..3}
  u16* outp = attnout + ((size_t)(b * SEQ + token)) * MODELD + hh * HDIM;
#pragma unroll
  for (int dblk = 0; dblk < 2; ++dblk) {
#pragma unroll
    for (int g = 0; g < 4; ++g) {
      float v0, v1, v2, v3;
      if (dblk == 0) {
        v0 = o0[4 * g + 0]; v1 = o0[4 * g + 1]; v2 = o0[4 * g + 2]; v3 = o0[4 * g + 3];
      } else {
        v0 = o1[4 * g + 0]; v1 = o1[4 * g + 1]; v2 = o1[4 * g + 2]; v3 = o1[4 * g + 3];
      }
      u32x2 ow;
      ow[0] = cvtpk(v0 * inv, v1 * inv);
      ow[1] = cvtpk(v2 * inv, v3 * inv);
      *(u32x2*)(outp + dblk * 32 + g * 8 + h * 4) = ow;
    }
  }
}

// ---------------- launch ----------------
extern "C" void kernel_launch(void* const* d_in, const int* in_sizes, int n_in,
                              void* d_out, int out_size, void* d_ws, size_t ws_size,
                              hipStream_t stream) {
  const float* x       = (const float*)d_in[0];
  const unsigned int* mask = (const unsigned int*)d_in[1];
  const float* w_qkv   = (const float*)d_in[2];
  const float* wq_base = (const float*)d_in[3];
  const float* bq      = (const float*)d_in[4];
  const float* wq_A    = (const float*)d_in[5];
  const float* wq_B    = (const float*)d_in[6];
  const float* wv_base = (const float*)d_in[7];
  const float* bv      = (const float*)d_in[8];
  const float* wv_A    = (const float*)d_in[9];
  const float* wv_B    = (const float*)d_in[10];
  const float* w_out   = (const float*)d_in[11];
  const float* b_out   = (const float*)d_in[12];
  float* out = (float*)d_out;

  char* ws = (char*)d_ws;
  u16* xb      = (u16*)(ws);                 // 8 MB  (reused as attnout)
  u16* wcomb   = (u16*)(ws + 8388608);       // 6 MB
  u16* woutb   = (u16*)(ws + 14680064);      // 2 MB
  u16* qws     = (u16*)(ws + 16777216);      // 8 MB (row-major)
  u16* kws     = (u16*)(ws + 25165824);      // 8 MB (frag-major)
  u16* vws     = (u16*)(ws + 33554432);      // 8 MB (frag-major)
  float* biasc = (float*)(ws + 50331648);    // 12 KB
  float* maskf = (float*)(ws + 50343936);    // 16 KB (additive f32)
  u16* attnout = xb;                          // xb dead after gemm_qkv

  prep_cast<<<4096, 256, 0, stream>>>(x, xb);          // 4M elems
  prep_cast<<<1024, 256, 0, stream>>>(w_out, woutb);   // 1M elems
  prep_mask<<<1, 1024, 0, stream>>>(mask, maskf);
  prep_w<<<3072, 256, 0, stream>>>(w_qkv, wq_base, bq, wq_A, wq_B,
                                   wv_base, bv, wv_A, wv_B, wcomb, biasc);

  gemm128<0><<<dim3(QKVCOLS / 128, MROWS / 128), 256, 0, stream>>>(
      xb, wcomb, biasc, qws, kws, vws, nullptr);

  flash_attn<<<512, 256, 0, stream>>>(qws, kws, vws, maskf, attnout);

  gemm128<1><<<dim3(MODELD / 128, MROWS / 128), 256, 0, stream>>>(
      attnout, woutb, b_out, nullptr, nullptr, nullptr, out);
}